// Round 7
// baseline (388.010 us; speedup 1.0000x reference)
//
#include <hip/hip_runtime.h>
#include <math.h>

#define N_NODES 100000
#define N_EDGES 640000

typedef __bf16 bf16x8 __attribute__((ext_vector_type(8)));
typedef float f32x4 __attribute__((ext_vector_type(4)));

__device__ __forceinline__ unsigned short f2b(float x) {
  unsigned int u = __float_as_uint(x);
  u = (u + 0x7FFFu + ((u >> 16) & 1u)) >> 16;   // RNE
  return (unsigned short)u;
}
__device__ __forceinline__ float blo(unsigned int v) { return __uint_as_float(v << 16); }
__device__ __forceinline__ float bhi(unsigned int v) { return __uint_as_float(v & 0xFFFF0000u); }

// fragment-major ushort index into W: [ct][kc][q][m][e]  (nn = ct*16+m, k = kc*32+q*8+e)
__device__ __forceinline__ int fragidx(int nn, int k) {
  int ct = nn >> 4, m = nn & 15;
  int kc = k >> 5, q = (k >> 3) & 3, e = k & 7;
  return (((ct * 4 + kc) * 4 + q) * 16 + m) * 8 + e;
}

// H (128-feat) layout: 8 slices of 16 feats, slice-major:
//   H[s*RS + node*16 + (f&15)], RS=(n+1)*16 ushorts (node n = zero row).
// X (aggregated, 128-feat): X[s*RSX + node*16 + (f&15)], RSX=n*16.

// ---------------- edge prep ----------------

__global__ __launch_bounds__(256) void k_count(const int* __restrict__ dst, int* __restrict__ deg, int e) {
  int i = blockIdx.x * 256 + threadIdx.x;
  if (i < e) atomicAdd(&deg[dst[i]], 1);
}

__global__ __launch_bounds__(256) void k_alloc(const int* __restrict__ deg, int* __restrict__ row_ptr,
                                               int* __restrict__ fillpos, int* __restrict__ col,
                                               float* __restrict__ dinv, int* __restrict__ counter, int n) {
  __shared__ int sdata[256];
  __shared__ int sbase;
  int tid = threadIdx.x;
  int i = blockIdx.x * 256 + tid;
  int d = (i < n) ? deg[i] : 0;
  sdata[tid] = d;
  __syncthreads();
  for (int off = 1; off < 256; off <<= 1) {
    int v = (tid >= off) ? sdata[tid - off] : 0;
    __syncthreads();
    sdata[tid] += v;
    __syncthreads();
  }
  if (tid == 255) sbase = atomicAdd(counter, sdata[255]);
  __syncthreads();
  int base = sbase;
  if (i < n) {
    int rp = base + sdata[tid] - d;   // exclusive prefix
    row_ptr[i] = rp;
    fillpos[i] = rp + 1;              // slot 0 = self-loop
    col[rp] = i;
    dinv[i] = rsqrtf((float)d);
  }
}

__global__ __launch_bounds__(256) void k_fill(const int* __restrict__ src, const int* __restrict__ dst,
                                              int* __restrict__ fillpos, int* __restrict__ col, int e) {
  int i = blockIdx.x * 256 + threadIdx.x;
  if (i < e) {
    int d = dst[i];
    int p = atomicAdd(&fillpos[d], 1);
    col[p] = src[i];
  }
}

// ---- merged prep: deg/counter init + W1/2/3 -> fragment-major bf16 + W4 padded fragment-major ----

__global__ __launch_bounds__(256) void k_prep0(const float* __restrict__ W1, const float* __restrict__ W2,
                                               const float* __restrict__ W3, const float* __restrict__ W4,
                                               unsigned short* __restrict__ Wt, unsigned short* __restrict__ Wt4,
                                               unsigned short* __restrict__ Ha, unsigned short* __restrict__ Hc,
                                               unsigned short* __restrict__ H4,
                                               int* __restrict__ deg, int* __restrict__ counter, int n) {
  int b = blockIdx.x;
  int tid = threadIdx.x;
  if (b < 391) {
    int i = b * 256 + tid;
    if (i < n) deg[i] = 1;            // self-loop
    if (i == 0) *counter = 0;
  } else if (b < 583) {
    int bb = b - 391;
    const float* W = (bb < 64) ? W1 : (bb < 128) ? W2 : W3;
    unsigned short* D = Wt + ((bb < 64) ? 0 : (bb < 128) ? 16384 : 32768);
    int idx = (bb & 63) * 256 + tid;            // [0,16384)
    int k = idx >> 7, nn = idx & 127;           // W[k][nn]
    D[fragidx(nn, k)] = f2b(W[idx]);
  } else if (b < 607) {
    int idx = (b - 583) * 256 + tid;            // [0,6144)
    int nn = idx >> 7, k = idx & 127;           // nn in [0,48)
    Wt4[fragidx(nn, k)] = (nn < 40) ? f2b(W4[(size_t)k * 40 + nn]) : (unsigned short)0;
  } else if (b == 607) {
    // zero row (node n) in all 8 slices of Ha and Hc
    size_t RS = (size_t)(n + 1) * 16;
    int which = tid >> 7;            // 0=Ha 1=Hc
    int idx = tid & 127;
    int s = idx >> 4, o = idx & 15;
    unsigned short* P = which ? Hc : Ha;
    P[(size_t)s * RS + (size_t)n * 16 + o] = 0;
  } else {
    if (tid < 48) H4[(size_t)n * 40 + tid] = 0;          // 40 + pad
  }
}

#define SXP 136   // (unused by current kernels; kept for reference)

// ---------------- layer-1 GEMM: fp32 X streamed, B-fragments from global, H out slice-major ----------------

__global__ __launch_bounds__(256) void k_gemm1(const float* __restrict__ X,
                                               const unsigned short* __restrict__ Wt,
                                               const float* __restrict__ dinv,
                                               unsigned short* __restrict__ H, int n) {
  int tid = threadIdx.x;
  int row0 = blockIdx.x * 64;
  int wave = tid >> 6, lane = tid & 63;
  int m = lane & 15, q = lane >> 4;
  int grow = row0 + wave * 16 + m;
  if (grow >= n) grow = n - 1;
  const float4* X4 = (const float4*)X;
  uint4 a4[4];
#pragma unroll
  for (int kc = 0; kc < 4; ++kc) {
    float4 f0 = X4[(size_t)grow * 32 + kc * 8 + q * 2];
    float4 f1 = X4[(size_t)grow * 32 + kc * 8 + q * 2 + 1];
    a4[kc].x = (unsigned int)f2b(f0.x) | ((unsigned int)f2b(f0.y) << 16);
    a4[kc].y = (unsigned int)f2b(f0.z) | ((unsigned int)f2b(f0.w) << 16);
    a4[kc].z = (unsigned int)f2b(f1.x) | ((unsigned int)f2b(f1.y) << 16);
    a4[kc].w = (unsigned int)f2b(f1.z) | ((unsigned int)f2b(f1.w) << 16);
  }
  const bf16x8* Wf = (const bf16x8*)Wt;   // fragment-major
  f32x4 acc[8];
#pragma unroll
  for (int ct = 0; ct < 8; ++ct) acc[ct] = (f32x4){0.f, 0.f, 0.f, 0.f};
#pragma unroll
  for (int kc = 0; kc < 4; ++kc) {
    bf16x8 a = *(bf16x8*)&a4[kc];
#pragma unroll
    for (int ct = 0; ct < 8; ++ct) {
      bf16x8 b = Wf[(ct * 4 + kc) * 64 + lane];
      acc[ct] = __builtin_amdgcn_mfma_f32_16x16x32_bf16(a, b, acc[ct], 0, 0, 0);
    }
  }
  size_t RS = (size_t)(n + 1) * 16;
#pragma unroll
  for (int r = 0; r < 4; ++r) {
    int row = row0 + wave * 16 + q * 4 + r;
    if (row < n) {
      float di = dinv[row];
#pragma unroll
      for (int ct = 0; ct < 8; ++ct)
        H[(size_t)ct * RS + (size_t)row * 16 + m] = f2b(acc[ct][r] * di);
    }
  }
}

// ---------------- feature-sliced aggregation: X_s = relu(dinv*agg(H_s) + bias_s) ----------------
// slice s = blockIdx % 8 -> (round-robin dispatch) all slice-s blocks on XCD s; that XCD's
// L2 holds the whole 3.2 MB slice -> gather is L2-resident. 2 lanes per node (16 B each),
// serial neighbor loop with 8-deep clamped unroll (clamp -> zero row n).

__global__ __launch_bounds__(256) void k_aggs(const unsigned short* __restrict__ Hin,
                                              const int* __restrict__ col,
                                              const int* __restrict__ row_ptr,
                                              const int* __restrict__ deg,
                                              const float* __restrict__ dinv,
                                              const float* __restrict__ bias,
                                              unsigned short* __restrict__ Xout, int n) {
  int s = blockIdx.x & 7;
  int g = blockIdx.x >> 3;
  int node = g * 128 + (threadIdx.x >> 1);
  int half = threadIdx.x & 1;
  if (node >= n) return;
  const size_t RS = (size_t)(n + 1) * 16;
  const size_t RSX = (size_t)n * 16;
  const uint4* Hs = (const uint4*)(Hin + (size_t)s * RS);   // 2 uint4 per node row
  int start = row_ptr[node];
  int cnt = deg[node];
  float a0 = 0.f, a1 = 0.f, a2 = 0.f, a3 = 0.f, a4 = 0.f, a5 = 0.f, a6 = 0.f, a7 = 0.f;
  for (int j = 0; j < cnt; j += 8) {
    uint4 v[8];
#pragma unroll
    for (int k2 = 0; k2 < 8; ++k2) {
      int jj = j + k2;
      int c = (jj < cnt) ? col[start + jj] : n;    // clamp -> zero row
      v[k2] = Hs[(size_t)c * 2 + half];
    }
#pragma unroll
    for (int k2 = 0; k2 < 8; ++k2) {
      a0 += blo(v[k2].x); a1 += bhi(v[k2].x);
      a2 += blo(v[k2].y); a3 += bhi(v[k2].y);
      a4 += blo(v[k2].z); a5 += bhi(v[k2].z);
      a6 += blo(v[k2].w); a7 += bhi(v[k2].w);
    }
  }
  float di = dinv[node];
  const float4* B4 = (const float4*)(bias + s * 16 + half * 8);
  float4 bb0 = B4[0], bb1 = B4[1];
  float o0 = fmaf(a0, di, bb0.x), o1 = fmaf(a1, di, bb0.y);
  float o2 = fmaf(a2, di, bb0.z), o3 = fmaf(a3, di, bb0.w);
  float o4 = fmaf(a4, di, bb1.x), o5 = fmaf(a5, di, bb1.y);
  float o6 = fmaf(a6, di, bb1.z), o7 = fmaf(a7, di, bb1.w);
  o0 = o0 > 0.f ? o0 : 0.f; o1 = o1 > 0.f ? o1 : 0.f;
  o2 = o2 > 0.f ? o2 : 0.f; o3 = o3 > 0.f ? o3 : 0.f;
  o4 = o4 > 0.f ? o4 : 0.f; o5 = o5 > 0.f ? o5 : 0.f;
  o6 = o6 > 0.f ? o6 : 0.f; o7 = o7 > 0.f ? o7 : 0.f;
  uint4 w;
  w.x = (unsigned int)f2b(o0) | ((unsigned int)f2b(o1) << 16);
  w.y = (unsigned int)f2b(o2) | ((unsigned int)f2b(o3) << 16);
  w.z = (unsigned int)f2b(o4) | ((unsigned int)f2b(o5) << 16);
  w.w = (unsigned int)f2b(o6) | ((unsigned int)f2b(o7) << 16);
  *(uint4*)&Xout[(size_t)s * RSX + (size_t)node * 16 + half * 8] = w;
}

// ---------------- GEMM over slice-major X: Hout = dinv*(X W), W staged in LDS fragment-major ----------------
// NCT=8: Hout slice-major [(n+1)*16 per slice]. NCT=3: Hout row-major [n+1][40] (layer 4).

template <int NCT>
__global__ __launch_bounds__(256) void k_gemms(const unsigned short* __restrict__ X,
                                               const unsigned short* __restrict__ Wt,
                                               const float* __restrict__ dinv,
                                               unsigned short* __restrict__ Hout, int n) {
  __shared__ unsigned short sW[NCT * 2048];   // fragment-major: [(ct*4+kc)*64 + lane] x bf16x8
  int tid = threadIdx.x;
  int row0 = blockIdx.x * 64;
  {
    const uint4* W4 = (const uint4*)Wt;
    uint4* sW4 = (uint4*)sW;
#pragma unroll
    for (int i = 0; i < NCT; ++i) sW4[i * 256 + tid] = W4[i * 256 + tid];
  }
  int wave = tid >> 6, lane = tid & 63;
  int m = lane & 15, q = lane >> 4;
  int grow = row0 + wave * 16 + m;
  if (grow >= n) grow = n - 1;
  const size_t RSX = (size_t)n * 16;
  uint4 a4[4];
#pragma unroll
  for (int kc = 0; kc < 4; ++kc) {
    int s = kc * 2 + (q >> 1);
    a4[kc] = *(const uint4*)&X[(size_t)s * RSX + (size_t)grow * 16 + (q & 1) * 8];
  }
  __syncthreads();
  const bf16x8* Wl = (const bf16x8*)sW;
  f32x4 acc[NCT];
#pragma unroll
  for (int ct = 0; ct < NCT; ++ct) acc[ct] = (f32x4){0.f, 0.f, 0.f, 0.f};
#pragma unroll
  for (int kc = 0; kc < 4; ++kc) {
    bf16x8 a = *(bf16x8*)&a4[kc];
#pragma unroll
    for (int ct = 0; ct < NCT; ++ct) {
      bf16x8 b = Wl[(ct * 4 + kc) * 64 + lane];
      acc[ct] = __builtin_amdgcn_mfma_f32_16x16x32_bf16(a, b, acc[ct], 0, 0, 0);
    }
  }
#pragma unroll
  for (int r = 0; r < 4; ++r) {
    int row = row0 + wave * 16 + q * 4 + r;
    if (row < n) {
      float di = dinv[row];
      if constexpr (NCT == 8) {
        size_t RS = (size_t)(n + 1) * 16;
#pragma unroll
        for (int ct = 0; ct < 8; ++ct)
          Hout[(size_t)ct * RS + (size_t)row * 16 + m] = f2b(acc[ct][r] * di);
      } else {
#pragma unroll
        for (int ct = 0; ct < NCT; ++ct) {
          int c = ct * 16 + m;
          if (c < 40) Hout[(size_t)row * 40 + c] = f2b(acc[ct][r] * di);
        }
      }
    }
  }
}

// ---------------- final aggregation F=40 + bias + log_softmax, 3-slice + 4-round prefetch ----------------

__global__ __launch_bounds__(256) void k_agg40_lsm(const unsigned short* __restrict__ H, const int* __restrict__ col,
                                                   const int* __restrict__ row_ptr, const int* __restrict__ deg,
                                                   const float* __restrict__ dinv, const float* __restrict__ bias,
                                                   float* __restrict__ out, int n) {
  int node = blockIdx.x * 4 + (threadIdx.x >> 6);
  int lane = threadIdx.x & 63;
  if (node >= n) return;
  const unsigned int* H1 = (const unsigned int*)H;   // 20 uints per row; row n = zeros
  int start = row_ptr[node];
  int cnt = deg[node];
  int cnt0 = (cnt < 63) ? cnt : 63;
  int myc = (lane < cnt0) ? col[start + lane] : n;
  int slice = (lane >= 20) + (lane >= 40);
  int pr = lane - slice * 20;
  pr = (pr > 19) ? 19 : pr;                          // lanes 60..63 duplicate slice2/pr19
  int rounds = (cnt0 + 2) / 3;
  float ax = 0.f, ay = 0.f;
  for (int rb = 0; rb < rounds; rb += 4) {           // 4 independent gathers in flight
    unsigned int v[4];
#pragma unroll
    for (int j = 0; j < 4; ++j) {
      int idx = (rb + j) * 3 + slice;
      idx = (idx > 63) ? 63 : idx;                   // lane 63 -> zero row
      int c = __shfl(myc, idx, 64);
      v[j] = H1[(size_t)c * 20 + pr];
    }
#pragma unroll
    for (int j = 0; j < 4; ++j) { ax += blo(v[j]); ay += bhi(v[j]); }
  }
  if (lane < 20) {
    for (int j = 63; j < cnt; ++j) {                 // rare deg>=64 tail
      int c = col[start + j];
      unsigned int v = H1[(size_t)c * 20 + pr];
      ax += blo(v);
      ay += bhi(v);
    }
  }
  // combine the 3 slices into lanes 0..19
  float ax1 = __shfl(ax, lane + 20, 64), ay1 = __shfl(ay, lane + 20, 64);
  float ax2 = __shfl(ax, lane + 40, 64), ay2 = __shfl(ay, lane + 40, 64);
  float di = dinv[node];
  float2 b2 = ((const float2*)bias)[pr];
  float c0 = fmaf(ax + ax1 + ax2, di, b2.x);
  float c1 = fmaf(ay + ay1 + ay2, di, b2.y);
  // log-softmax over 40 classes held as pairs in lanes 0..19
  float v = (lane < 20) ? fmaxf(c0, c1) : -INFINITY;
#pragma unroll
  for (int off = 32; off > 0; off >>= 1) v = fmaxf(v, __shfl_xor(v, off, 64));
  float e = (lane < 20) ? (__expf(c0 - v) + __expf(c1 - v)) : 0.f;
#pragma unroll
  for (int off = 32; off > 0; off >>= 1) e += __shfl_xor(e, off, 64);
  if (lane < 20) {
    float ls = v + __logf(e);
    ((float2*)out)[(size_t)node * 20 + lane] = make_float2(c0 - ls, c1 - ls);
  }
}

// ---------------- launcher ----------------

extern "C" void kernel_launch(void* const* d_in, const int* in_sizes, int n_in,
                              void* d_out, int out_size, void* d_ws, size_t ws_size,
                              hipStream_t stream) {
  const float* x  = (const float*)d_in[0];
  const int* edge = (const int*)d_in[1];
  const float* W1 = (const float*)d_in[2];
  const float* b1 = (const float*)d_in[3];
  const float* W2 = (const float*)d_in[4];
  const float* b2 = (const float*)d_in[5];
  const float* W3 = (const float*)d_in[6];
  const float* b3 = (const float*)d_in[7];
  const float* W4 = (const float*)d_in[8];
  const float* b4 = (const float*)d_in[9];
  float* out = (float*)d_out;

  const int n = N_NODES, E = N_EDGES;
  const int* srcp = edge;        // edge_index[0]
  const int* dstp = edge + E;    // edge_index[1]

  char* ws = (char*)d_ws;
  size_t off = 0;
  auto alloc = [&](size_t bytes) -> void* {
    void* p = ws + off;
    off = (off + bytes + 255) & ~(size_t)255;
    return p;
  };
  int*   deg     = (int*)alloc((size_t)n * 4);
  int*   row_ptr = (int*)alloc((size_t)n * 4);
  int*   fillpos = (int*)alloc((size_t)n * 4);
  float* dinv    = (float*)alloc((size_t)n * 4);
  int*   counter = (int*)alloc(256);
  int*   colx    = (int*)alloc((size_t)(E + n) * 4);
  unsigned short* Ha  = (unsigned short*)alloc((size_t)(n + 1) * 128 * 2);
  unsigned short* Hc  = (unsigned short*)alloc((size_t)(n + 1) * 128 * 2);
  unsigned short* Xc  = (unsigned short*)alloc((size_t)n * 128 * 2);
  unsigned short* H4  = (unsigned short*)alloc(((size_t)(n + 1) * 40 + 16) * 2);
  unsigned short* Wt  = (unsigned short*)alloc((size_t)3 * 128 * 128 * 2);
  unsigned short* Wt4 = (unsigned short*)alloc((size_t)48 * 128 * 2);
  (void)ws_size; (void)in_sizes; (void)n_in; (void)out_size;

  k_prep0<<<609, 256, 0, stream>>>(W1, W2, W3, W4, Wt, Wt4, Ha, Hc, H4, deg, counter, n);
  k_count<<<(E + 255) / 256, 256, 0, stream>>>(dstp, deg, E);
  k_alloc<<<(n + 255) / 256, 256, 0, stream>>>(deg, row_ptr, fillpos, colx, dinv, counter, n);
  k_fill <<<(E + 255) / 256, 256, 0, stream>>>(srcp, dstp, fillpos, colx, E);

  const int gg = (n + 63) / 64;                 // 64-node GEMM tiles
  const int gs = 8 * ((n + 127) / 128);         // 8 slices x 128-node groups
  const int ga = (n + 3) / 4;
  // layer 1
  k_gemm1<<<gg, 256, 0, stream>>>(x, Wt, dinv, Ha, n);
  k_aggs <<<gs, 256, 0, stream>>>(Ha, colx, row_ptr, deg, dinv, b1, Xc, n);
  // layer 2
  k_gemms<8><<<gg, 256, 0, stream>>>(Xc, Wt + 16384, dinv, Hc, n);
  k_aggs <<<gs, 256, 0, stream>>>(Hc, colx, row_ptr, deg, dinv, b2, Xc, n);
  // layer 3
  k_gemms<8><<<gg, 256, 0, stream>>>(Xc, Wt + 32768, dinv, Ha, n);
  k_aggs <<<gs, 256, 0, stream>>>(Ha, colx, row_ptr, deg, dinv, b3, Xc, n);
  // layer 4
  k_gemms<3><<<gg, 256, 0, stream>>>(Xc, Wt4, dinv, H4, n);
  k_agg40_lsm<<<ga, 256, 0, stream>>>(H4, colx, row_ptr, deg, dinv, b4, out, n);
}

// Round 9
// 318.461 us; speedup vs baseline: 1.2184x; 1.2184x over previous
//
#include <hip/hip_runtime.h>
#include <math.h>

#define N_NODES 100000
#define N_EDGES 640000

typedef __bf16 bf16x8 __attribute__((ext_vector_type(8)));
typedef float f32x4 __attribute__((ext_vector_type(4)));

__device__ __forceinline__ unsigned short f2b(float x) {
  unsigned int u = __float_as_uint(x);
  u = (u + 0x7FFFu + ((u >> 16) & 1u)) >> 16;   // RNE
  return (unsigned short)u;
}
__device__ __forceinline__ float blo(unsigned int v) { return __uint_as_float(v << 16); }
__device__ __forceinline__ float bhi(unsigned int v) { return __uint_as_float(v & 0xFFFF0000u); }

// ---------------- edge prep ----------------

__global__ __launch_bounds__(256) void k_count(const int* __restrict__ dst, int* __restrict__ deg, int e) {
  int i = blockIdx.x * 256 + threadIdx.x;
  if (i < e) atomicAdd(&deg[dst[i]], 1);
}

__global__ __launch_bounds__(256) void k_alloc(const int* __restrict__ deg, int* __restrict__ row_ptr,
                                               int* __restrict__ fillpos, int* __restrict__ col,
                                               float* __restrict__ dinv, int* __restrict__ counter, int n) {
  __shared__ int sdata[256];
  __shared__ int sbase;
  int tid = threadIdx.x;
  int i = blockIdx.x * 256 + tid;
  int d = (i < n) ? deg[i] : 0;
  sdata[tid] = d;
  __syncthreads();
  for (int off = 1; off < 256; off <<= 1) {
    int v = (tid >= off) ? sdata[tid - off] : 0;
    __syncthreads();
    sdata[tid] += v;
    __syncthreads();
  }
  if (tid == 255) sbase = atomicAdd(counter, sdata[255]);
  __syncthreads();
  int base = sbase;
  if (i < n) {
    int rp = base + sdata[tid] - d;   // exclusive prefix
    row_ptr[i] = rp;
    fillpos[i] = rp + 1;              // slot 0 = self-loop
    col[rp] = i;
    dinv[i] = rsqrtf((float)d);
  }
}

__global__ __launch_bounds__(256) void k_fill(const int* __restrict__ src, const int* __restrict__ dst,
                                              int* __restrict__ fillpos, int* __restrict__ col, int e) {
  int i = blockIdx.x * 256 + threadIdx.x;
  if (i < e) {
    int d = dst[i];
    int p = atomicAdd(&fillpos[d], 1);
    col[p] = src[i];
  }
}

// ---- merged prep: deg/counter init + W1/2/3 -> bf16 W^T + W4 -> 64-padded W^T + zero rows ----
// blocks 0..390: deg init; 391..582: W123; 583..614: W4 (64 rows); 615: Ha/Hc zero rows; 616: H4 zero row.

__global__ __launch_bounds__(256) void k_prep0(const float* __restrict__ W1, const float* __restrict__ W2,
                                               const float* __restrict__ W3, const float* __restrict__ W4,
                                               unsigned short* __restrict__ Wt, unsigned short* __restrict__ Wt4,
                                               unsigned short* __restrict__ Ha, unsigned short* __restrict__ Hc,
                                               unsigned short* __restrict__ H4,
                                               int* __restrict__ deg, int* __restrict__ counter, int n) {
  int b = blockIdx.x;
  int tid = threadIdx.x;
  if (b < 391) {
    int i = b * 256 + tid;
    if (i < n) deg[i] = 1;            // self-loop
    if (i == 0) *counter = 0;
  } else if (b < 583) {
    int bb = b - 391;
    const float* W = (bb < 64) ? W1 : (bb < 128) ? W2 : W3;
    unsigned short* D = Wt + ((bb < 64) ? 0 : (bb < 128) ? 16384 : 32768);
    int idx = (bb & 63) * 256 + tid;            // [0,16384)
    int k = idx >> 7, nn = idx & 127;
    D[nn * 128 + k] = f2b(W[idx]);
  } else if (b < 615) {
    int idx = (b - 583) * 256 + tid;            // [0,8192)
    int nn = idx >> 7, k = idx & 127;           // nn in [0,64)
    Wt4[nn * 128 + k] = (nn < 40) ? f2b(W4[(size_t)k * 40 + nn]) : (unsigned short)0;
  } else if (b == 615) {
    if (tid < 128) Ha[(size_t)n * 128 + tid] = 0;        // zero rows for gathers
    else Hc[(size_t)n * 128 + (tid - 128)] = 0;
  } else {
    if (tid < 64) H4[(size_t)n * 64 + tid] = 0;          // 64-col padded zero row
  }
}

#define SXP 136   // padded LDS stride in bf16 elems (conflict-free per prior measurements)

// ---------------- layer-1 GEMM: fp32 X read directly, bf16 MFMA, H = dinv*(X W1) ----------------

__global__ __launch_bounds__(256) void k_gemm1(const float* __restrict__ X,
                                               const unsigned short* __restrict__ Wt,
                                               const float* __restrict__ dinv,
                                               unsigned short* __restrict__ H, int n) {
  __shared__ unsigned short sW[128 * SXP];
  int tid = threadIdx.x;
  int row0 = blockIdx.x * 64;
  {
    const uint4* Wt4 = (const uint4*)Wt;
#pragma unroll
    for (int i = 0; i < 8; ++i) {
      int f = tid + i * 256;
      *(uint4*)&sW[(f >> 4) * SXP + (f & 15) * 8] = Wt4[f];
    }
  }
  int wave = tid >> 6, lane = tid & 63;
  int m = lane & 15, q = lane >> 4;
  int grow = row0 + wave * 16 + m;
  if (grow >= n) grow = n - 1;
  const float4* X4 = (const float4*)X;
  uint4 a4[4];
#pragma unroll
  for (int kc = 0; kc < 4; ++kc) {
    float4 f0 = X4[(size_t)grow * 32 + kc * 8 + q * 2];
    float4 f1 = X4[(size_t)grow * 32 + kc * 8 + q * 2 + 1];
    a4[kc].x = (unsigned int)f2b(f0.x) | ((unsigned int)f2b(f0.y) << 16);
    a4[kc].y = (unsigned int)f2b(f0.z) | ((unsigned int)f2b(f0.w) << 16);
    a4[kc].z = (unsigned int)f2b(f1.x) | ((unsigned int)f2b(f1.y) << 16);
    a4[kc].w = (unsigned int)f2b(f1.z) | ((unsigned int)f2b(f1.w) << 16);
  }
  __syncthreads();
  f32x4 acc[8];
#pragma unroll
  for (int ct = 0; ct < 8; ++ct) acc[ct] = (f32x4){0.f, 0.f, 0.f, 0.f};
#pragma unroll
  for (int kc = 0; kc < 4; ++kc) {
    bf16x8 a = *(bf16x8*)&a4[kc];
#pragma unroll
    for (int ct = 0; ct < 8; ++ct) {
      bf16x8 b = *(const bf16x8*)&sW[(ct * 16 + m) * SXP + kc * 32 + q * 8];
      acc[ct] = __builtin_amdgcn_mfma_f32_16x16x32_bf16(a, b, acc[ct], 0, 0, 0);
    }
  }
#pragma unroll
  for (int r = 0; r < 4; ++r) {
    int row = row0 + wave * 16 + q * 4 + r;
    if (row < n) {
      float di = dinv[row];
#pragma unroll
      for (int ct = 0; ct < 8; ++ct)
        H[(size_t)row * 128 + ct * 16 + m] = f2b(acc[ct][r] * di);
    }
  }
}

// ---------------- fused layer: Xrow = relu(agg(Hin)+bias); Hout = dinv*(Xrow W) ----------------
// R1 structure (best measured): quarter-wave gather, 8-deep ILP, sW SXP-staged, sX tile.
// NCT=8: Hout row-major [n+1][128]. NCT=4: Hout row-major [n+1][64] (layer 4, cols>=40 zero).

template <int NCT>
__global__ __launch_bounds__(256) void k_fag(const unsigned short* __restrict__ Hin,
                                             const int* __restrict__ col,
                                             const int* __restrict__ row_ptr,
                                             const int* __restrict__ deg,
                                             const float* __restrict__ dinv,
                                             const float* __restrict__ bias,
                                             const unsigned short* __restrict__ Wt,
                                             unsigned short* __restrict__ Hout, int n) {
  __shared__ unsigned short sW[NCT * 16 * SXP];
  __shared__ unsigned short sX[64 * SXP];
  int tid = threadIdx.x;
  int row0 = blockIdx.x * 64;
  {
    const uint4* W4 = (const uint4*)Wt;
#pragma unroll
    for (int i = 0; i < NCT; ++i) {
      int f = tid + i * 256;
      *(uint4*)&sW[(f >> 4) * SXP + (f & 15) * 8] = W4[f];
    }
  }
  // ---- aggregation phase ----
  int ql = tid & 15;
  int qbase = tid & 48;
  const uint4* Hg = (const uint4*)Hin;               // 16 uint4 per row; row n = zeros
  float4 b0 = ((const float4*)bias)[ql * 2];
  float4 b1 = ((const float4*)bias)[ql * 2 + 1];
  int starts[4], cnts[4], mycs[4];
#pragma unroll
  for (int it = 0; it < 4; ++it) {
    int node = row0 + (tid >> 4) + (it << 4);
    int nc = (node < n) ? node : 0;
    starts[it] = row_ptr[nc];
    cnts[it] = deg[nc];
  }
#pragma unroll
  for (int it = 0; it < 4; ++it) {
    int c0 = (cnts[it] < 15) ? cnts[it] : 15;
    mycs[it] = (ql < c0) ? col[starts[it] + ql] : n;
  }
#pragma unroll 1
  for (int it = 0; it < 4; ++it) {
    int node = row0 + (tid >> 4) + (it << 4);
    if (node >= n) break;                            // uniform within quarter-wave
    int cnt = cnts[it];
    int cnt0 = (cnt < 15) ? cnt : 15;
    int myc = mycs[it];
    float s0 = 0.f, s1 = 0.f, s2 = 0.f, s3 = 0.f, s4 = 0.f, s5 = 0.f, s6 = 0.f, s7 = 0.f;
    for (int base = 0; base < cnt0; base += 8) {
      uint4 v[8];
#pragma unroll
      for (int jj = 0; jj < 8; ++jj) {
        int idx = base + jj;
        idx = (idx > 15) ? 15 : idx;                 // lane 15 of quarter always zero-row
        int c = __shfl(myc, qbase + idx, 64);
        v[jj] = Hg[(size_t)c * 16 + ql];
      }
#pragma unroll
      for (int jj = 0; jj < 8; ++jj) {
        s0 += blo(v[jj].x); s1 += bhi(v[jj].x);
        s2 += blo(v[jj].y); s3 += bhi(v[jj].y);
        s4 += blo(v[jj].z); s5 += bhi(v[jj].z);
        s6 += blo(v[jj].w); s7 += bhi(v[jj].w);
      }
    }
    for (int j = 15; j < cnt; ++j) {                 // deg>15 tail (rare)
      int c = col[starts[it] + j];
      uint4 v = Hg[(size_t)c * 16 + ql];
      s0 += blo(v.x); s1 += bhi(v.x);
      s2 += blo(v.y); s3 += bhi(v.y);
      s4 += blo(v.z); s5 += bhi(v.z);
      s6 += blo(v.w); s7 += bhi(v.w);
    }
    float di = dinv[node];
    float o0 = fmaf(s0, di, b0.x), o1 = fmaf(s1, di, b0.y);
    float o2 = fmaf(s2, di, b0.z), o3 = fmaf(s3, di, b0.w);
    float o4 = fmaf(s4, di, b1.x), o5 = fmaf(s5, di, b1.y);
    float o6 = fmaf(s6, di, b1.z), o7 = fmaf(s7, di, b1.w);
    o0 = o0 > 0.f ? o0 : 0.f; o1 = o1 > 0.f ? o1 : 0.f;
    o2 = o2 > 0.f ? o2 : 0.f; o3 = o3 > 0.f ? o3 : 0.f;
    o4 = o4 > 0.f ? o4 : 0.f; o5 = o5 > 0.f ? o5 : 0.f;
    o6 = o6 > 0.f ? o6 : 0.f; o7 = o7 > 0.f ? o7 : 0.f;
    uint4 w;
    w.x = (unsigned int)f2b(o0) | ((unsigned int)f2b(o1) << 16);
    w.y = (unsigned int)f2b(o2) | ((unsigned int)f2b(o3) << 16);
    w.z = (unsigned int)f2b(o4) | ((unsigned int)f2b(o5) << 16);
    w.w = (unsigned int)f2b(o6) | ((unsigned int)f2b(o7) << 16);
    *(uint4*)&sX[(node - row0) * SXP + ql * 8] = w;
  }
  __syncthreads();
  // ---- MFMA phase ----
  int wave = tid >> 6, lane = tid & 63;
  int m = lane & 15, q = lane >> 4;
  int grow = row0 + wave * 16 + m;
  if (grow >= n) grow = n - 1;
  int lrow = grow - row0;
  uint4 a4[4];
#pragma unroll
  for (int kc = 0; kc < 4; ++kc) a4[kc] = *(const uint4*)&sX[lrow * SXP + kc * 32 + q * 8];
  f32x4 acc[NCT];
#pragma unroll
  for (int ct = 0; ct < NCT; ++ct) acc[ct] = (f32x4){0.f, 0.f, 0.f, 0.f};
#pragma unroll
  for (int kc = 0; kc < 4; ++kc) {
    bf16x8 a = *(bf16x8*)&a4[kc];
#pragma unroll
    for (int ct = 0; ct < NCT; ++ct) {
      bf16x8 b = *(const bf16x8*)&sW[(ct * 16 + m) * SXP + kc * 32 + q * 8];
      acc[ct] = __builtin_amdgcn_mfma_f32_16x16x32_bf16(a, b, acc[ct], 0, 0, 0);
    }
  }
#pragma unroll
  for (int r = 0; r < 4; ++r) {
    int row = row0 + wave * 16 + q * 4 + r;
    if (row < n) {
      float di = dinv[row];
      if constexpr (NCT == 8) {
#pragma unroll
        for (int ct = 0; ct < 8; ++ct)
          Hout[(size_t)row * 128 + ct * 16 + m] = f2b(acc[ct][r] * di);
      } else {
#pragma unroll
        for (int ct = 0; ct < NCT; ++ct)
          Hout[(size_t)row * 64 + ct * 16 + m] = f2b(acc[ct][r] * di);
      }
    }
  }
}

// ---------------- final aggregation over 64-padded H4 + bias + log_softmax ----------------
// 8-lane octet per node; lane ol reads one uint4 (16 B) of each neighbor's 128 B row ->
// perfectly coalesced 8 requests/edge (vs 20 x 4 B before). 8-deep ILP per round.
// Octet-local log-softmax via __shfl_xor(.., 8); lanes 0..4 hold the 40 real classes.

__global__ __launch_bounds__(256) void k_agg40_lsm(const unsigned short* __restrict__ H, const int* __restrict__ col,
                                                   const int* __restrict__ row_ptr, const int* __restrict__ deg,
                                                   const float* __restrict__ dinv, const float* __restrict__ bias,
                                                   float* __restrict__ out, int n) {
  int node = blockIdx.x * 32 + (threadIdx.x >> 3);
  int ol = threadIdx.x & 7;
  int obase = threadIdx.x & 56;                      // octet base within wave
  if (node >= n) return;
  const uint4* Hg = (const uint4*)H;                 // 8 uint4 per 64-col row; row n = zeros
  int start = row_ptr[node];
  int cnt = deg[node];
  float a0 = 0.f, a1 = 0.f, a2 = 0.f, a3 = 0.f, a4 = 0.f, a5 = 0.f, a6 = 0.f, a7 = 0.f;
  for (int rb = 0; rb < cnt; rb += 8) {
    int myc = (rb + ol < cnt) ? col[start + rb + ol] : n;   // clamp -> zero row
    uint4 v[8];
#pragma unroll
    for (int jj = 0; jj < 8; ++jj) {
      int c = __shfl(myc, obase + jj, 64);
      v[jj] = Hg[(size_t)c * 8 + ol];
    }
#pragma unroll
    for (int jj = 0; jj < 8; ++jj) {
      a0 += blo(v[jj].x); a1 += bhi(v[jj].x);
      a2 += blo(v[jj].y); a3 += bhi(v[jj].y);
      a4 += blo(v[jj].z); a5 += bhi(v[jj].z);
      a6 += blo(v[jj].w); a7 += bhi(v[jj].w);
    }
  }
  float di = dinv[node];
  bool valid = (ol < 5);                             // cols ol*8..ol*8+7 < 40
  float c0, c1, c2, c3, c4, c5, c6, c7;
  if (valid) {
    float4 bb0 = ((const float4*)bias)[ol * 2];
    float4 bb1 = ((const float4*)bias)[ol * 2 + 1];
    c0 = fmaf(a0, di, bb0.x); c1 = fmaf(a1, di, bb0.y);
    c2 = fmaf(a2, di, bb0.z); c3 = fmaf(a3, di, bb0.w);
    c4 = fmaf(a4, di, bb1.x); c5 = fmaf(a5, di, bb1.y);
    c6 = fmaf(a6, di, bb1.z); c7 = fmaf(a7, di, bb1.w);
  } else {
    c0 = c1 = c2 = c3 = c4 = c5 = c6 = c7 = -INFINITY;
  }
  float m = fmaxf(fmaxf(fmaxf(c0, c1), fmaxf(c2, c3)), fmaxf(fmaxf(c4, c5), fmaxf(c6, c7)));
  m = fmaxf(m, __shfl_xor(m, 1, 8));
  m = fmaxf(m, __shfl_xor(m, 2, 8));
  m = fmaxf(m, __shfl_xor(m, 4, 8));
  float e = valid ? (__expf(c0 - m) + __expf(c1 - m) + __expf(c2 - m) + __expf(c3 - m) +
                     __expf(c4 - m) + __expf(c5 - m) + __expf(c6 - m) + __expf(c7 - m)) : 0.f;
  e += __shfl_xor(e, 1, 8);
  e += __shfl_xor(e, 2, 8);
  e += __shfl_xor(e, 4, 8);
  if (valid) {
    float ls = m + __logf(e);
    float4 o0 = {c0 - ls, c1 - ls, c2 - ls, c3 - ls};
    float4 o1 = {c4 - ls, c5 - ls, c6 - ls, c7 - ls};
    *(float4*)&out[(size_t)node * 40 + ol * 8] = o0;
    *(float4*)&out[(size_t)node * 40 + ol * 8 + 4] = o1;
  }
}

// ---------------- launcher ----------------

extern "C" void kernel_launch(void* const* d_in, const int* in_sizes, int n_in,
                              void* d_out, int out_size, void* d_ws, size_t ws_size,
                              hipStream_t stream) {
  const float* x  = (const float*)d_in[0];
  const int* edge = (const int*)d_in[1];
  const float* W1 = (const float*)d_in[2];
  const float* b1 = (const float*)d_in[3];
  const float* W2 = (const float*)d_in[4];
  const float* b2 = (const float*)d_in[5];
  const float* W3 = (const float*)d_in[6];
  const float* b3 = (const float*)d_in[7];
  const float* W4 = (const float*)d_in[8];
  const float* b4 = (const float*)d_in[9];
  float* out = (float*)d_out;

  const int n = N_NODES, E = N_EDGES;
  const int* srcp = edge;        // edge_index[0]
  const int* dstp = edge + E;    // edge_index[1]

  char* ws = (char*)d_ws;
  size_t off = 0;
  auto alloc = [&](size_t bytes) -> void* {
    void* p = ws + off;
    off = (off + bytes + 255) & ~(size_t)255;
    return p;
  };
  int*   deg     = (int*)alloc((size_t)n * 4);
  int*   row_ptr = (int*)alloc((size_t)n * 4);
  int*   fillpos = (int*)alloc((size_t)n * 4);
  float* dinv    = (float*)alloc((size_t)n * 4);
  int*   counter = (int*)alloc(256);
  int*   colx    = (int*)alloc((size_t)(E + n) * 4);
  unsigned short* Ha  = (unsigned short*)alloc((size_t)(n + 1) * 128 * 2);
  unsigned short* Hc  = (unsigned short*)alloc((size_t)(n + 1) * 128 * 2);
  unsigned short* H4  = (unsigned short*)alloc((size_t)(n + 1) * 64 * 2);
  unsigned short* Wt  = (unsigned short*)alloc((size_t)3 * 128 * 128 * 2);
  unsigned short* Wt4 = (unsigned short*)alloc((size_t)64 * 128 * 2);
  (void)ws_size; (void)in_sizes; (void)n_in; (void)out_size;

  k_prep0<<<617, 256, 0, stream>>>(W1, W2, W3, W4, Wt, Wt4, Ha, Hc, H4, deg, counter, n);
  k_count<<<(E + 255) / 256, 256, 0, stream>>>(dstp, deg, E);
  k_alloc<<<(n + 255) / 256, 256, 0, stream>>>(deg, row_ptr, fillpos, colx, dinv, counter, n);
  k_fill <<<(E + 255) / 256, 256, 0, stream>>>(srcp, dstp, fillpos, colx, E);

  const int gg = (n + 63) / 64, ga = (n + 31) / 32;
  // layer 1 GEMM
  k_gemm1<<<gg, 256, 0, stream>>>(x, Wt, dinv, Ha, n);
  // fused agg(L1)+GEMM(L2)
  k_fag<8><<<gg, 256, 0, stream>>>(Ha, colx, row_ptr, deg, dinv, b1, Wt + 16384, Hc, n);
  // fused agg(L2)+GEMM(L3)
  k_fag<8><<<gg, 256, 0, stream>>>(Hc, colx, row_ptr, deg, dinv, b2, Wt + 32768, Ha, n);
  // fused agg(L3)+GEMM(L4, 64 padded cols)
  k_fag<4><<<gg, 256, 0, stream>>>(Ha, colx, row_ptr, deg, dinv, b3, Wt4, H4, n);
  // final aggregation + log_softmax (octet, 16 B/lane gathers)
  k_agg40_lsm<<<ga, 256, 0, stream>>>(H4, colx, row_ptr, deg, dinv, b4, out, n);
}